// Round 3
// baseline (3359.459 us; speedup 1.0000x reference)
//
#include <hip/hip_runtime.h>
#include <hip/hip_fp16.h>

// Many2OneRNN: B=64, S=4096, I=256, H=256, O=128
// Phase 1 (k_xp):  xp[b,t,h] = x[b,t,:]·Wax_w[h,:] + Wax_b[h]  (MFMA f16, f16 out)
// Phase 2 (k_rnn): a = tanh(xp_t + Waa*a + Waa_b), 1 block/chain, 1024 thr
//   (16 waves, 4/SIMD).  Lane l: k = l&15 owns K-slice [k*16,k*16+16); group
//   g = l>>4; rows rbase=w*16+g*4 .. +4, skewed: slot i -> row rbase+((k+i)&3).
//   Per thread/step: 2 ds_read_b128 (broadcast), 32 fdot2, 11-DPP rotate-
//   reduce (pure VALU), 5-op tanh, 1 dup ds_write_b16.  Weights: 32 VGPRs.
// Phase 3: folded into last k_rnn: out = sigmoid(Wya*a + Wya_b).

typedef _Float16 f16x8 __attribute__((ext_vector_type(8)));
typedef _Float16 f16x2 __attribute__((ext_vector_type(2)));
typedef float    f32x4 __attribute__((ext_vector_type(4)));

#define FDOT2(a, b, c) __builtin_amdgcn_fdot2((a), (b), (c), false)

// row_ror:D within each 16-lane row: dst lane i gets src lane (i-D)&15
template <int D>
__device__ __forceinline__ float rorf(float v) {
    return __builtin_bit_cast(float,
        __builtin_amdgcn_update_dpp(0, __builtin_bit_cast(int, v),
                                    0x120 + D, 0xF, 0xF, true));
}

// ---------------------------------------------------------------------------
// Phase 1: xp GEMM.  grid = T_C blocks (64 rows each), 512 threads.
// ---------------------------------------------------------------------------
__global__ __launch_bounds__(512) void k_xp(
    const float* __restrict__ x, const float* __restrict__ Ww,
    const float* __restrict__ Wb, _Float16* __restrict__ xp,
    int c, int T_C, int logT)
{
    __shared__ __align__(16) _Float16 As[64 * 264];  // pad 256->264 halves
    const int tid  = threadIdx.x;
    const int lane = tid & 63;
    const int wv   = tid >> 6;   // 0..7
    const int l15  = lane & 15;
    const int lk   = lane >> 4;  // 0..3
    const int n0   = wv * 32;

    // --- B fragments (Wax_w rows = N dim, K contiguous) in registers
    f16x8 bfr[2][8];
#pragma unroll
    for (int nt = 0; nt < 2; ++nt) {
        const float* wrow = Ww + (size_t)(n0 + nt * 16 + l15) * 256;
#pragma unroll
        for (int kt = 0; kt < 8; ++kt) {
            const float4* wp = (const float4*)(wrow + kt * 32 + lk * 8);
            float4 v0 = wp[0], v1 = wp[1];
            f16x8 f;
            f[0] = (_Float16)v0.x; f[1] = (_Float16)v0.y;
            f[2] = (_Float16)v0.z; f[3] = (_Float16)v0.w;
            f[4] = (_Float16)v1.x; f[5] = (_Float16)v1.y;
            f[6] = (_Float16)v1.z; f[7] = (_Float16)v1.w;
            bfr[nt][kt] = f;
        }
    }
    const float bias0 = Wb[n0 + l15];
    const float bias1 = Wb[n0 + 16 + l15];

    // --- stage A tile (64 rows x 256 K) f32 -> f16 LDS
    {
        const int arow = tid >> 3;           // 0..63
        const int acol = (tid & 7) * 32;     // 0..224
        const int r    = blockIdx.x * 64 + arow;
        const int bb   = r >> logT;
        const int tl   = r & (T_C - 1);
        const float4* s4 = (const float4*)(x + ((size_t)(bb * 4096 + c * T_C + tl) << 8) + acol);
        _Float16* d = As + arow * 264 + acol;
#pragma unroll
        for (int q = 0; q < 4; ++q) {
            float4 v0 = s4[2 * q], v1 = s4[2 * q + 1];
            f16x8 p;
            p[0] = (_Float16)v0.x; p[1] = (_Float16)v0.y;
            p[2] = (_Float16)v0.z; p[3] = (_Float16)v0.w;
            p[4] = (_Float16)v1.x; p[5] = (_Float16)v1.y;
            p[6] = (_Float16)v1.z; p[7] = (_Float16)v1.w;
            *(f16x8*)(d + q * 8) = p;
        }
    }
    __syncthreads();

    f32x4 acc[4][2] = {};
#pragma unroll
    for (int kt = 0; kt < 8; ++kt) {
#pragma unroll
        for (int mt = 0; mt < 4; ++mt) {
            f16x8 af = *(const f16x8*)(As + (mt * 16 + l15) * 264 + kt * 32 + lk * 8);
            acc[mt][0] = __builtin_amdgcn_mfma_f32_16x16x32_f16(af, bfr[0][kt], acc[mt][0], 0, 0, 0);
            acc[mt][1] = __builtin_amdgcn_mfma_f32_16x16x32_f16(af, bfr[1][kt], acc[mt][1], 0, 0, 0);
        }
    }

    // --- store xp (f16)
    const size_t base = (size_t)blockIdx.x * 64;
#pragma unroll
    for (int mt = 0; mt < 4; ++mt) {
#pragma unroll
        for (int nt = 0; nt < 2; ++nt) {
            const int   colg = n0 + nt * 16 + l15;
            const float bias = (nt == 0) ? bias0 : bias1;
#pragma unroll
            for (int r2 = 0; r2 < 4; ++r2) {
                size_t row = base + mt * 16 + lk * 4 + r2;
                xp[(row << 8) + colg] = (_Float16)(acc[mt][nt][r2] + bias);
            }
        }
    }
}

// ---------------------------------------------------------------------------
// Phase 2: recurrence.  grid = 64 blocks, 1024 threads (16 waves, 4/SIMD).
// a double-buffered in LDS [16 chunks][24 halves] (48 B stride: 16-lane b128
// read = 2-way bank alias (free) with 4-way same-address broadcast (free)).
// ---------------------------------------------------------------------------
__global__ __launch_bounds__(1024) void k_rnn(
    const _Float16* __restrict__ xp, const float* __restrict__ Waa,
    const float* __restrict__ Wab, const float* __restrict__ Wya,
    const float* __restrict__ Wyb, float* __restrict__ out,
    unsigned short* __restrict__ a_state,
    int c, int T_C, int is_last)
{
    __shared__ __align__(16) _Float16 aL[2][16][24];
    __shared__ float afin[256];
    const int tid   = threadIdx.x;
    const int lane  = tid & 63;
    const int w     = tid >> 6;      // 0..15
    const int k     = lane & 15;     // K-thread: slice [k*16, k*16+16)
    const int g     = lane >> 4;     // 0..3
    const int rbase = w * 16 + g * 4;
    const int myrow = rbase + (k & 3);   // row this lane finalizes
    const int b     = blockIdx.x;

    // --- weights: slot i -> row rbase+((k+i)&3), K-contiguous f16x2 (32 VGPR)
    f16x2 wr[4][8];
#pragma unroll
    for (int i = 0; i < 4; ++i) {
        const float4* wp = (const float4*)(Waa + (size_t)(rbase + ((k + i) & 3)) * 256 + k * 16);
#pragma unroll
        for (int q = 0; q < 4; ++q) {
            float4 v = wp[q];
            f16x2 t0; t0[0] = (_Float16)v.x; t0[1] = (_Float16)v.y;
            f16x2 t1; t1[0] = (_Float16)v.z; t1[1] = (_Float16)v.w;
            wr[i][2 * q]     = t0;
            wr[i][2 * q + 1] = t1;
        }
    }
    const float bias = Wab[myrow];

    // --- init a buffer 0
    if (tid < 256) {
        unsigned short v = 0;
        if (c != 0) v = a_state[b * 256 + tid];
        aL[0][tid >> 4][tid & 15] = __builtin_bit_cast(_Float16, v);
    }
    __syncthreads();

    // --- xp register prefetch, depth 8 (f16, 2 B/thread/step)
    const _Float16* xph = xp + (((size_t)b * T_C) << 8) + myrow;
    float xr[8];
#pragma unroll
    for (int j = 0; j < 8; ++j) xr[j] = (float)xph[(size_t)j << 8];

    const _Float16* rp0 = &aL[0][k][0];
    const _Float16* rp1 = &aL[1][k][0];
    _Float16* wq0 = &aL[1][w][g * 4 + (k & 3)];  // write when reading buf0
    _Float16* wq1 = &aL[0][w][g * 4 + (k & 3)];

    for (int tb = 0; tb < T_C; tb += 8) {
#pragma unroll
        for (int j = 0; j < 8; ++j) {
            const _Float16* rp = (j & 1) ? rp1 : rp0;   // static after unroll
            uint4 r0 = *(const uint4*)(rp);
            uint4 r1 = *(const uint4*)(rp + 8);

            float bx = bias + xr[j];   // read xr before prefetch overwrite
            if (tb + j + 8 < T_C) xr[j] = (float)xph[((size_t)(tb + j + 8)) << 8];

            f16x2 a2[8];
            a2[0] = __builtin_bit_cast(f16x2, r0.x);
            a2[1] = __builtin_bit_cast(f16x2, r0.y);
            a2[2] = __builtin_bit_cast(f16x2, r0.z);
            a2[3] = __builtin_bit_cast(f16x2, r0.w);
            a2[4] = __builtin_bit_cast(f16x2, r1.x);
            a2[5] = __builtin_bit_cast(f16x2, r1.y);
            a2[6] = __builtin_bit_cast(f16x2, r1.z);
            a2[7] = __builtin_bit_cast(f16x2, r1.w);

            float s0 = 0.f, s1 = 0.f, s2 = 0.f, s3 = 0.f;
#pragma unroll
            for (int q = 0; q < 8; ++q) {
                s0 = FDOT2(wr[0][q], a2[q], s0);
                s1 = FDOT2(wr[1][q], a2[q], s1);
                s2 = FDOT2(wr[2][q], a2[q], s2);
                s3 = FDOT2(wr[3][q], a2[q], s3);
            }

            // 16-lane rotate-reduce (period-4 skew): acc[k] = total(row k&3)
            float p0 = s0 + rorf<8>(s0);
            float p1 = s1 + rorf<8>(s1);
            float p2 = s2 + rorf<8>(s2);
            float p3 = s3 + rorf<8>(s3);
            float q0 = p0 + rorf<4>(p0);
            float q1 = p1 + rorf<4>(p1);
            float q2 = p2 + rorf<4>(p2);
            float q3 = p3 + rorf<4>(p3);
            float acc = (q0 + rorf<1>(q1)) + (rorf<2>(q2) + rorf<3>(q3));

            float z = bx + acc;
            // tanh(z) = 1 - 2/(1+e^{2z})   (inf-safe at both ends)
            float e2 = __expf(2.f * z);
            float a  = fmaf(-2.f, __builtin_amdgcn_rcpf(e2 + 1.f), 1.f);
            _Float16 ah = (_Float16)a;
            // all 4 dup lanes (k, k+4, k+8, k+12) write same row/value: benign
            *((j & 1) ? wq1 : wq0) = ah;
            if (tb + j == T_C - 1) {
                afin[myrow] = a;
                a_state[b * 256 + myrow] = __builtin_bit_cast(unsigned short, ah);
            }
            // LDS-only barrier: xp prefetch (vmcnt) stays in flight.
            asm volatile("s_waitcnt lgkmcnt(0)" ::: "memory");
            __builtin_amdgcn_s_barrier();
            asm volatile("" ::: "memory");
        }
    }

    // --- Phase 3: out = sigmoid(Wya * a_last + Wyb), last chunk only
    if (is_last) {
        const int o  = tid >> 3;   // 0..127
        const int k8 = tid & 7;    // 8-way K split within wave
        const float4* wp = (const float4*)(Wya + (size_t)o * 256 + k8 * 32);
        const float4* ap = (const float4*)(afin + k8 * 32);
        float s = 0.f;
#pragma unroll
        for (int i = 0; i < 8; ++i) {
            float4 wv4 = wp[i];
            float4 a4  = ap[i];
            s += wv4.x * a4.x + wv4.y * a4.y + wv4.z * a4.z + wv4.w * a4.w;
        }
        s += __shfl_xor(s, 1);
        s += __shfl_xor(s, 2);
        s += __shfl_xor(s, 4);
        if (k8 == 0)
            out[b * 128 + o] = __builtin_amdgcn_rcpf(1.f + __expf(-(s + Wyb[o])));
    }
}

// ---------------------------------------------------------------------------
extern "C" void kernel_launch(void* const* d_in, const int* in_sizes, int n_in,
                              void* d_out, int out_size, void* d_ws, size_t ws_size,
                              hipStream_t stream)
{
    (void)in_sizes; (void)n_in; (void)out_size;
    const float* x    = (const float*)d_in[0];
    const float* Waxw = (const float*)d_in[1];
    const float* Waxb = (const float*)d_in[2];
    const float* Waaw = (const float*)d_in[3];
    const float* Waab = (const float*)d_in[4];
    const float* Wyaw = (const float*)d_in[5];
    const float* Wyab = (const float*)d_in[6];
    float* out = (float*)d_out;

    // Adaptive chunking over timesteps so the f16 xp chunk fits in d_ws.
    int T_C = 4096, logT = 12;
    while (T_C > 32 && (size_t)64 * T_C * 256 * 2 + 32768 > ws_size) { T_C >>= 1; --logT; }

    _Float16* xp = (_Float16*)d_ws;
    unsigned short* a_state =
        (unsigned short*)((char*)d_ws + (size_t)64 * T_C * 256 * 2);

    const int nc = 4096 / T_C;
    for (int ci = 0; ci < nc; ++ci) {
        k_xp<<<dim3(T_C), dim3(512), 0, stream>>>(x, Waxw, Waxb, xp, ci, T_C, logT);
        k_rnn<<<dim3(64), dim3(1024), 0, stream>>>(xp, Waaw, Waab, Wyaw, Wyab,
                                                   out, a_state, ci, T_C, ci == nc - 1);
    }
}

// Round 4
// 2270.998 us; speedup vs baseline: 1.4793x; 1.4793x over previous
//
#include <hip/hip_runtime.h>
#include <hip/hip_fp16.h>

// Many2OneRNN: B=64, S=4096, I=256, H=256, O=128
// Phase 1 (k_xp):  xp3[b][h][t] = x[b,t,:]·Wax_w[h,:] + Wax_b[h]  (MFMA f16,
//                  f16 out, t-contiguous so k_rnn loads 8 steps per b128)
// Phase 2 (k_rnn): a = tanh(xp_t + Waa*a + Waa_b), 1 block/chain, 1024 thr
//   (16 waves, 4/SIMD).  Lane l: k = l&15 owns K-slice [k*16,k*16+16); group
//   g = l>>4; rows rbase=w*16+g*4..+4, skewed: slot i -> row rbase+((k+i)&3).
//   Per thread/step: 2 ds_read_b128 (broadcast), 32 fdot2, 11-DPP rotate-
//   reduce (pure VALU), 5-op tanh, predicated ds_write_b16 (k<4 lanes).
// Phase 3: folded into last k_rnn: out = sigmoid(Wya*a + Wya_b).

typedef _Float16 f16x8 __attribute__((ext_vector_type(8)));
typedef _Float16 f16x4 __attribute__((ext_vector_type(4)));
typedef _Float16 f16x2 __attribute__((ext_vector_type(2)));
typedef float    f32x4 __attribute__((ext_vector_type(4)));

#define FDOT2(a, b, c) __builtin_amdgcn_fdot2((a), (b), (c), false)

// row_ror:D within each 16-lane row: dst lane i gets src lane (i-D)&15
template <int D>
__device__ __forceinline__ float rorf(float v) {
    return __builtin_bit_cast(float,
        __builtin_amdgcn_update_dpp(0, __builtin_bit_cast(int, v),
                                    0x120 + D, 0xF, 0xF, true));
}

// ---------------------------------------------------------------------------
// Phase 1: xp GEMM.  grid = T_C blocks (64 t-rows each), 512 threads.
// Output layout xp3[b][h][t_local] (f16, t-contiguous).
// ---------------------------------------------------------------------------
__global__ __launch_bounds__(512) void k_xp(
    const float* __restrict__ x, const float* __restrict__ Ww,
    const float* __restrict__ Wb, _Float16* __restrict__ xp,
    int c, int T_C, int logT)
{
    __shared__ __align__(16) _Float16 As[64 * 264];  // pad 256->264 halves
    const int tid  = threadIdx.x;
    const int lane = tid & 63;
    const int wv   = tid >> 6;   // 0..7
    const int l15  = lane & 15;
    const int lk   = lane >> 4;  // 0..3
    const int n0   = wv * 32;

    // --- B fragments (Wax_w rows = N dim, K contiguous) in registers
    f16x8 bfr[2][8];
#pragma unroll
    for (int nt = 0; nt < 2; ++nt) {
        const float* wrow = Ww + (size_t)(n0 + nt * 16 + l15) * 256;
#pragma unroll
        for (int kt = 0; kt < 8; ++kt) {
            const float4* wp = (const float4*)(wrow + kt * 32 + lk * 8);
            float4 v0 = wp[0], v1 = wp[1];
            f16x8 f;
            f[0] = (_Float16)v0.x; f[1] = (_Float16)v0.y;
            f[2] = (_Float16)v0.z; f[3] = (_Float16)v0.w;
            f[4] = (_Float16)v1.x; f[5] = (_Float16)v1.y;
            f[6] = (_Float16)v1.z; f[7] = (_Float16)v1.w;
            bfr[nt][kt] = f;
        }
    }
    const float bias0 = Wb[n0 + l15];
    const float bias1 = Wb[n0 + 16 + l15];

    // --- stage A tile (64 rows x 256 K) f32 -> f16 LDS
    {
        const int arow = tid >> 3;           // 0..63
        const int acol = (tid & 7) * 32;     // 0..224
        const int r    = blockIdx.x * 64 + arow;
        const int bb   = r >> logT;
        const int tl   = r & (T_C - 1);
        const float4* s4 = (const float4*)(x + ((size_t)(bb * 4096 + c * T_C + tl) << 8) + acol);
        _Float16* d = As + arow * 264 + acol;
#pragma unroll
        for (int q = 0; q < 4; ++q) {
            float4 v0 = s4[2 * q], v1 = s4[2 * q + 1];
            f16x8 p;
            p[0] = (_Float16)v0.x; p[1] = (_Float16)v0.y;
            p[2] = (_Float16)v0.z; p[3] = (_Float16)v0.w;
            p[4] = (_Float16)v1.x; p[5] = (_Float16)v1.y;
            p[6] = (_Float16)v1.z; p[7] = (_Float16)v1.w;
            *(f16x8*)(d + q * 8) = p;
        }
    }
    __syncthreads();

    f32x4 acc[4][2] = {};
#pragma unroll
    for (int kt = 0; kt < 8; ++kt) {
#pragma unroll
        for (int mt = 0; mt < 4; ++mt) {
            f16x8 af = *(const f16x8*)(As + (mt * 16 + l15) * 264 + kt * 32 + lk * 8);
            acc[mt][0] = __builtin_amdgcn_mfma_f32_16x16x32_f16(af, bfr[0][kt], acc[mt][0], 0, 0, 0);
            acc[mt][1] = __builtin_amdgcn_mfma_f32_16x16x32_f16(af, bfr[1][kt], acc[mt][1], 0, 0, 0);
        }
    }

    // --- store xp3[b][h][t]: pack 4 t-contiguous halves -> one 8B store
    const int base = blockIdx.x * 64;
#pragma unroll
    for (int mt = 0; mt < 4; ++mt) {
        const int rr  = base + mt * 16 + lk * 4;   // 4-aligned t-run, one b
        const int bb2 = rr >> logT;
        const int tt  = rr & (T_C - 1);
#pragma unroll
        for (int nt = 0; nt < 2; ++nt) {
            const int   h    = n0 + nt * 16 + l15;
            const float bias = (nt == 0) ? bias0 : bias1;
            f16x4 pk;
#pragma unroll
            for (int r2 = 0; r2 < 4; ++r2) pk[r2] = (_Float16)(acc[mt][nt][r2] + bias);
            *(f16x4*)(xp + ((size_t)(bb2 * 256 + h)) * T_C + tt) = pk;
        }
    }
}

// ---------------------------------------------------------------------------
// Phase 2: recurrence.  grid = 64 blocks, 1024 threads (16 waves, 4/SIMD).
// a double-buffered in LDS [16 chunks][24 halves] (48 B stride: 16-lane b128
// read = 2-way bank alias (free) + 4-way same-address broadcast (free)).
// ---------------------------------------------------------------------------
__global__ __launch_bounds__(1024) void k_rnn(
    const _Float16* __restrict__ xp, const float* __restrict__ Waa,
    const float* __restrict__ Wab, const float* __restrict__ Wya,
    const float* __restrict__ Wyb, float* __restrict__ out,
    unsigned short* __restrict__ a_state,
    int c, int T_C, int is_last)
{
    __shared__ __align__(16) _Float16 aL[2][16][24];
    __shared__ float afin[256];
    const int tid   = threadIdx.x;
    const int lane  = tid & 63;
    const int w     = tid >> 6;      // 0..15
    const int k     = lane & 15;     // K-thread: slice [k*16, k*16+16)
    const int g     = lane >> 4;     // 0..3
    const int rbase = w * 16 + g * 4;
    const int myrow = rbase + (k & 3);   // row this lane finalizes
    const int b     = blockIdx.x;
    const bool wlane = (k & 12) == 0;    // 16 writer lanes cover all 16 rows

    // --- weights: slot i -> row rbase+((k+i)&3), K-contiguous f16x2 (32 VGPR)
    f16x2 wr[4][8];
#pragma unroll
    for (int i = 0; i < 4; ++i) {
        const float4* wp = (const float4*)(Waa + (size_t)(rbase + ((k + i) & 3)) * 256 + k * 16);
#pragma unroll
        for (int q = 0; q < 4; ++q) {
            float4 v = wp[q];
            f16x2 t0; t0[0] = (_Float16)v.x; t0[1] = (_Float16)v.y;
            f16x2 t1; t1[0] = (_Float16)v.z; t1[1] = (_Float16)v.w;
            wr[i][2 * q]     = t0;
            wr[i][2 * q + 1] = t1;
        }
    }
    const float bias = Wab[myrow];

    // --- init a buffer 0
    if (tid < 256) {
        unsigned short v = 0;
        if (c != 0) v = a_state[b * 256 + tid];
        aL[0][tid >> 4][tid & 15] = __builtin_bit_cast(_Float16, v);
    }
    __syncthreads();

    // --- xp stream: one b128 per 8 steps (t-contiguous layout)
    const _Float16* xph = xp + ((size_t)(b * 256 + myrow)) * T_C;
    f16x8 xq = *(const f16x8*)(xph);

    const _Float16* rp0 = &aL[0][k][0];
    const _Float16* rp1 = &aL[1][k][0];
    _Float16* wq0 = &aL[1][w][g * 4 + k];  // valid for wlane only (k<4)
    _Float16* wq1 = &aL[0][w][g * 4 + k];

#define RNN_STEP(J, FIN)                                                     \
    {                                                                        \
        const _Float16* rp = ((J) & 1) ? rp1 : rp0;                          \
        uint4 r0 = *(const uint4*)(rp);                                      \
        uint4 r1 = *(const uint4*)(rp + 8);                                  \
        float bx = bias + (float)xq[(J)];                                    \
        f16x2 a2[8];                                                         \
        a2[0] = __builtin_bit_cast(f16x2, r0.x);                             \
        a2[1] = __builtin_bit_cast(f16x2, r0.y);                             \
        a2[2] = __builtin_bit_cast(f16x2, r0.z);                             \
        a2[3] = __builtin_bit_cast(f16x2, r0.w);                             \
        a2[4] = __builtin_bit_cast(f16x2, r1.x);                             \
        a2[5] = __builtin_bit_cast(f16x2, r1.y);                             \
        a2[6] = __builtin_bit_cast(f16x2, r1.z);                             \
        a2[7] = __builtin_bit_cast(f16x2, r1.w);                             \
        float s0 = 0.f, s1 = 0.f, s2 = 0.f, s3 = 0.f;                        \
        _Pragma("unroll")                                                    \
        for (int q = 0; q < 8; ++q) {                                        \
            s0 = FDOT2(wr[0][q], a2[q], s0);                                 \
            s1 = FDOT2(wr[1][q], a2[q], s1);                                 \
            s2 = FDOT2(wr[2][q], a2[q], s2);                                 \
            s3 = FDOT2(wr[3][q], a2[q], s3);                                 \
        }                                                                    \
        float p0 = s0 + rorf<8>(s0);                                         \
        float p1 = s1 + rorf<8>(s1);                                         \
        float p2 = s2 + rorf<8>(s2);                                         \
        float p3 = s3 + rorf<8>(s3);                                         \
        float q0 = p0 + rorf<4>(p0);                                         \
        float q1 = p1 + rorf<4>(p1);                                         \
        float q2 = p2 + rorf<4>(p2);                                         \
        float q3 = p3 + rorf<4>(p3);                                         \
        float acc = (q0 + rorf<1>(q1)) + (rorf<2>(q2) + rorf<3>(q3));        \
        float z  = bx + acc;                                                 \
        float e2 = __expf(2.f * z);                                          \
        float a  = fmaf(-2.f, __builtin_amdgcn_rcpf(e2 + 1.f), 1.f);         \
        _Float16 ah = (_Float16)a;                                           \
        if (wlane) *(((J) & 1) ? wq1 : wq0) = ah;                            \
        if (FIN) {                                                           \
            afin[myrow] = a;                                                 \
            a_state[b * 256 + myrow] = __builtin_bit_cast(unsigned short, ah);\
        }                                                                    \
        asm volatile("s_waitcnt lgkmcnt(0)" ::: "memory");                   \
        __builtin_amdgcn_s_barrier();                                        \
        asm volatile("" ::: "memory");                                       \
    }

    for (int tb = 0; tb + 8 < T_C; tb += 8) {
        f16x8 xn = *(const f16x8*)(xph + tb + 8);   // scalar-guarded-free: always valid here
        RNN_STEP(0, false) RNN_STEP(1, false) RNN_STEP(2, false) RNN_STEP(3, false)
        RNN_STEP(4, false) RNN_STEP(5, false) RNN_STEP(6, false) RNN_STEP(7, false)
        xq = xn;
    }
    // peeled tail (last 8 steps): finalize on j==7
    RNN_STEP(0, false) RNN_STEP(1, false) RNN_STEP(2, false) RNN_STEP(3, false)
    RNN_STEP(4, false) RNN_STEP(5, false) RNN_STEP(6, false) RNN_STEP(7, true)
#undef RNN_STEP

    // --- Phase 3: out = sigmoid(Wya * a_last + Wyb), last chunk only
    if (is_last) {
        const int o  = tid >> 3;   // 0..127
        const int k8 = tid & 7;    // 8-way K split within wave
        const float4* wp = (const float4*)(Wya + (size_t)o * 256 + k8 * 32);
        const float4* ap = (const float4*)(afin + k8 * 32);
        float s = 0.f;
#pragma unroll
        for (int i = 0; i < 8; ++i) {
            float4 wv4 = wp[i];
            float4 a4  = ap[i];
            s += wv4.x * a4.x + wv4.y * a4.y + wv4.z * a4.z + wv4.w * a4.w;
        }
        s += __shfl_xor(s, 1);
        s += __shfl_xor(s, 2);
        s += __shfl_xor(s, 4);
        if (k8 == 0)
            out[b * 128 + o] = __builtin_amdgcn_rcpf(1.f + __expf(-(s + Wyb[o])));
    }
}

// ---------------------------------------------------------------------------
extern "C" void kernel_launch(void* const* d_in, const int* in_sizes, int n_in,
                              void* d_out, int out_size, void* d_ws, size_t ws_size,
                              hipStream_t stream)
{
    (void)in_sizes; (void)n_in; (void)out_size;
    const float* x    = (const float*)d_in[0];
    const float* Waxw = (const float*)d_in[1];
    const float* Waxb = (const float*)d_in[2];
    const float* Waaw = (const float*)d_in[3];
    const float* Waab = (const float*)d_in[4];
    const float* Wyaw = (const float*)d_in[5];
    const float* Wyab = (const float*)d_in[6];
    float* out = (float*)d_out;

    // Adaptive chunking over timesteps so the f16 xp chunk fits in d_ws.
    int T_C = 4096, logT = 12;
    while (T_C > 32 && (size_t)64 * T_C * 256 * 2 + 32768 > ws_size) { T_C >>= 1; --logT; }

    _Float16* xp = (_Float16*)d_ws;
    unsigned short* a_state =
        (unsigned short*)((char*)d_ws + (size_t)64 * T_C * 256 * 2);

    const int nc = 4096 / T_C;
    for (int ci = 0; ci < nc; ++ci) {
        k_xp<<<dim3(T_C), dim3(512), 0, stream>>>(x, Waxw, Waxb, xp, ci, T_C, logT);
        k_rnn<<<dim3(64), dim3(1024), 0, stream>>>(xp, Waaw, Waab, Wyaw, Wyab,
                                                   out, a_state, ci, T_C, ci == nc - 1);
    }
}

// Round 6
// 2239.881 us; speedup vs baseline: 1.4998x; 1.0139x over previous
//
#include <hip/hip_runtime.h>
#include <hip/hip_fp16.h>

// Many2OneRNN: B=64, S=4096, I=256, H=256, O=128
// Phase 1 (k_xp):  xp3[b][h][t] = x[b,t,:]·Wax_w[h,:] + Wax_b[h]  (MFMA f16,
//                  f16 out, t-contiguous so k_rnn loads 8 steps per b128)
// Phase 2 (k_rnn): a = tanh(xp_t + Waa*a + Waa_b), 1 block/chain, 1024 thr
//   (16 waves, 4/SIMD).  __launch_bounds__(1024,4) sets the true occupancy
//   (grid=64 -> 1 block/CU) so the 32-dword weight array stays in arch VGPRs
//   instead of AGPR-parking (R4: VGPR_Count=40 + ~32 accvgpr_read/step).
//   Lane l: k = l&15 owns K-slice [k*16,k*16+16); g = l>>4; rows
//   rbase=w*16+g*4..+4, skewed: slot i -> row rbase+((k+i)&3).
//   Per thread/step: 2 ds_read_b128 (broadcast), 32 fdot2, 11 DPP rotate-
//   reduce (intrinsic update_dpp: compiler inserts DPP hazard nops — raw
//   asm DPP corrupted lanes in R5), 5-op tanh, predicated ds_write_b16.
// Phase 3: folded into last k_rnn: out = sigmoid(Wya*a + Wya_b).

typedef _Float16 f16x8 __attribute__((ext_vector_type(8)));
typedef _Float16 f16x4 __attribute__((ext_vector_type(4)));
typedef _Float16 f16x2 __attribute__((ext_vector_type(2)));
typedef float    f32x4 __attribute__((ext_vector_type(4)));

#define FDOT2(a, b, c) __builtin_amdgcn_fdot2((a), (b), (c), false)

// row_ror:D within each 16-lane row: dst lane i gets src lane (i-D)&15
template <int D>
__device__ __forceinline__ float rorf(float v) {
    return __builtin_bit_cast(float,
        __builtin_amdgcn_update_dpp(0, __builtin_bit_cast(int, v),
                                    0x120 + D, 0xF, 0xF, true));
}

// ---------------------------------------------------------------------------
// Phase 1: xp GEMM.  grid = T_C blocks (64 t-rows each), 512 threads.
// Output layout xp3[b][h][t_local] (f16, t-contiguous).
// ---------------------------------------------------------------------------
__global__ __launch_bounds__(512) void k_xp(
    const float* __restrict__ x, const float* __restrict__ Ww,
    const float* __restrict__ Wb, _Float16* __restrict__ xp,
    int c, int T_C, int logT)
{
    __shared__ __align__(16) _Float16 As[64 * 264];  // pad 256->264 halves
    const int tid  = threadIdx.x;
    const int lane = tid & 63;
    const int wv   = tid >> 6;   // 0..7
    const int l15  = lane & 15;
    const int lk   = lane >> 4;  // 0..3
    const int n0   = wv * 32;

    // --- B fragments (Wax_w rows = N dim, K contiguous) in registers
    f16x8 bfr[2][8];
#pragma unroll
    for (int nt = 0; nt < 2; ++nt) {
        const float* wrow = Ww + (size_t)(n0 + nt * 16 + l15) * 256;
#pragma unroll
        for (int kt = 0; kt < 8; ++kt) {
            const float4* wp = (const float4*)(wrow + kt * 32 + lk * 8);
            float4 v0 = wp[0], v1 = wp[1];
            f16x8 f;
            f[0] = (_Float16)v0.x; f[1] = (_Float16)v0.y;
            f[2] = (_Float16)v0.z; f[3] = (_Float16)v0.w;
            f[4] = (_Float16)v1.x; f[5] = (_Float16)v1.y;
            f[6] = (_Float16)v1.z; f[7] = (_Float16)v1.w;
            bfr[nt][kt] = f;
        }
    }
    const float bias0 = Wb[n0 + l15];
    const float bias1 = Wb[n0 + 16 + l15];

    // --- stage A tile (64 rows x 256 K) f32 -> f16 LDS
    {
        const int arow = tid >> 3;           // 0..63
        const int acol = (tid & 7) * 32;     // 0..224
        const int r    = blockIdx.x * 64 + arow;
        const int bb   = r >> logT;
        const int tl   = r & (T_C - 1);
        const float4* s4 = (const float4*)(x + ((size_t)(bb * 4096 + c * T_C + tl) << 8) + acol);
        _Float16* d = As + arow * 264 + acol;
#pragma unroll
        for (int q = 0; q < 4; ++q) {
            float4 v0 = s4[2 * q], v1 = s4[2 * q + 1];
            f16x8 p;
            p[0] = (_Float16)v0.x; p[1] = (_Float16)v0.y;
            p[2] = (_Float16)v0.z; p[3] = (_Float16)v0.w;
            p[4] = (_Float16)v1.x; p[5] = (_Float16)v1.y;
            p[6] = (_Float16)v1.z; p[7] = (_Float16)v1.w;
            *(f16x8*)(d + q * 8) = p;
        }
    }
    __syncthreads();

    f32x4 acc[4][2] = {};
#pragma unroll
    for (int kt = 0; kt < 8; ++kt) {
#pragma unroll
        for (int mt = 0; mt < 4; ++mt) {
            f16x8 af = *(const f16x8*)(As + (mt * 16 + l15) * 264 + kt * 32 + lk * 8);
            acc[mt][0] = __builtin_amdgcn_mfma_f32_16x16x32_f16(af, bfr[0][kt], acc[mt][0], 0, 0, 0);
            acc[mt][1] = __builtin_amdgcn_mfma_f32_16x16x32_f16(af, bfr[1][kt], acc[mt][1], 0, 0, 0);
        }
    }

    // --- store xp3[b][h][t]: pack 4 t-contiguous halves -> one 8B store
    const int base = blockIdx.x * 64;
#pragma unroll
    for (int mt = 0; mt < 4; ++mt) {
        const int rr  = base + mt * 16 + lk * 4;   // 4-aligned t-run, one b
        const int bb2 = rr >> logT;
        const int tt  = rr & (T_C - 1);
#pragma unroll
        for (int nt = 0; nt < 2; ++nt) {
            const int   h    = n0 + nt * 16 + l15;
            const float bias = (nt == 0) ? bias0 : bias1;
            f16x4 pk;
#pragma unroll
            for (int r2 = 0; r2 < 4; ++r2) pk[r2] = (_Float16)(acc[mt][nt][r2] + bias);
            *(f16x4*)(xp + ((size_t)(bb2 * 256 + h)) * T_C + tt) = pk;
        }
    }
}

// ---------------------------------------------------------------------------
// Phase 2: recurrence.  grid = 64 blocks, 1024 threads (16 waves, 4/SIMD).
// a double-buffered in LDS [16 chunks][24 halves] (48 B stride: 16-lane b128
// read = 2-way bank alias (free) + 4-way same-address broadcast (free)).
// ---------------------------------------------------------------------------
__global__ __launch_bounds__(1024, 4) void k_rnn(
    const _Float16* __restrict__ xp, const float* __restrict__ Waa,
    const float* __restrict__ Wab, const float* __restrict__ Wya,
    const float* __restrict__ Wyb, float* __restrict__ out,
    unsigned short* __restrict__ a_state,
    int c, int T_C, int is_last)
{
    __shared__ __align__(16) _Float16 aL[2][16][24];
    __shared__ float afin[256];
    const int tid   = threadIdx.x;
    const int lane  = tid & 63;
    const int w     = tid >> 6;      // 0..15
    const int k     = lane & 15;     // K-thread: slice [k*16, k*16+16)
    const int g     = lane >> 4;     // 0..3
    const int rbase = w * 16 + g * 4;
    const int myrow = rbase + (k & 3);   // row this lane finalizes
    const int b     = blockIdx.x;
    const bool wlane = (k & 12) == 0;    // 16 writer lanes cover all 16 rows

    // --- weights: slot i -> row rbase+((k+i)&3), K-contiguous f16x2 (32 VGPR)
    f16x2 wr[4][8];
#pragma unroll
    for (int i = 0; i < 4; ++i) {
        const float4* wp = (const float4*)(Waa + (size_t)(rbase + ((k + i) & 3)) * 256 + k * 16);
#pragma unroll
        for (int q = 0; q < 4; ++q) {
            float4 v = wp[q];
            f16x2 t0; t0[0] = (_Float16)v.x; t0[1] = (_Float16)v.y;
            f16x2 t1; t1[0] = (_Float16)v.z; t1[1] = (_Float16)v.w;
            wr[i][2 * q]     = t0;
            wr[i][2 * q + 1] = t1;
        }
    }
    const float bias = Wab[myrow];

    // --- init a buffer 0
    if (tid < 256) {
        unsigned short v = 0;
        if (c != 0) v = a_state[b * 256 + tid];
        aL[0][tid >> 4][tid & 15] = __builtin_bit_cast(_Float16, v);
    }
    __syncthreads();

    // --- xp stream: one b128 per 8 steps (t-contiguous layout)
    const _Float16* xph = xp + ((size_t)(b * 256 + myrow)) * T_C;
    f16x8 xq = *(const f16x8*)(xph);
    float bx[8];
#pragma unroll
    for (int j = 0; j < 8; ++j) bx[j] = bias + (float)xq[j];  // same math as R4

    const _Float16* rp0 = &aL[0][k][0];
    const _Float16* rp1 = &aL[1][k][0];
    _Float16* wq0 = &aL[1][w][g * 4 + k];  // valid for wlane only (k<4)
    _Float16* wq1 = &aL[0][w][g * 4 + k];

#define RNN_STEP(J, FIN)                                                     \
    {                                                                        \
        const _Float16* rp = ((J) & 1) ? rp1 : rp0;                          \
        uint4 r0 = *(const uint4*)(rp);                                      \
        uint4 r1 = *(const uint4*)(rp + 8);                                  \
        f16x2 a2[8];                                                         \
        a2[0] = __builtin_bit_cast(f16x2, r0.x);                             \
        a2[1] = __builtin_bit_cast(f16x2, r0.y);                             \
        a2[2] = __builtin_bit_cast(f16x2, r0.z);                             \
        a2[3] = __builtin_bit_cast(f16x2, r0.w);                             \
        a2[4] = __builtin_bit_cast(f16x2, r1.x);                             \
        a2[5] = __builtin_bit_cast(f16x2, r1.y);                             \
        a2[6] = __builtin_bit_cast(f16x2, r1.z);                             \
        a2[7] = __builtin_bit_cast(f16x2, r1.w);                             \
        float s0 = 0.f, s1 = 0.f, s2 = 0.f, s3 = 0.f;                        \
        _Pragma("unroll")                                                    \
        for (int q = 0; q < 8; ++q) {                                        \
            s0 = FDOT2(wr[0][q], a2[q], s0);                                 \
            s1 = FDOT2(wr[1][q], a2[q], s1);                                 \
            s2 = FDOT2(wr[2][q], a2[q], s2);                                 \
            s3 = FDOT2(wr[3][q], a2[q], s3);                                 \
        }                                                                    \
        float p0 = s0 + rorf<8>(s0);                                         \
        float p1 = s1 + rorf<8>(s1);                                         \
        float p2 = s2 + rorf<8>(s2);                                         \
        float p3 = s3 + rorf<8>(s3);                                         \
        float q0 = p0 + rorf<4>(p0);                                         \
        float q1 = p1 + rorf<4>(p1);                                         \
        float q2 = p2 + rorf<4>(p2);                                         \
        float q3 = p3 + rorf<4>(p3);                                         \
        float acc = (q0 + rorf<1>(q1)) + (rorf<2>(q2) + rorf<3>(q3));        \
        float z  = bx[(J)] + acc;                                            \
        float e2 = __expf(2.f * z);                                          \
        float a  = fmaf(-2.f, __builtin_amdgcn_rcpf(e2 + 1.f), 1.f);         \
        _Float16 ah = (_Float16)a;                                           \
        if (wlane) *(((J) & 1) ? wq1 : wq0) = ah;                            \
        if (FIN) {                                                           \
            afin[myrow] = a;                                                 \
            a_state[b * 256 + myrow] = __builtin_bit_cast(unsigned short, ah);\
        }                                                                    \
        asm volatile("s_waitcnt lgkmcnt(0)" ::: "memory");                   \
        __builtin_amdgcn_s_barrier();                                        \
        asm volatile("" ::: "memory");                                       \
    }

    for (int tb = 0; tb + 8 < T_C; tb += 8) {
        f16x8 xn = *(const f16x8*)(xph + tb + 8);   // always valid here
        RNN_STEP(0, false) RNN_STEP(1, false) RNN_STEP(2, false) RNN_STEP(3, false)
        RNN_STEP(4, false) RNN_STEP(5, false) RNN_STEP(6, false) RNN_STEP(7, false)
#pragma unroll
        for (int j = 0; j < 8; ++j) bx[j] = bias + (float)xn[j];
    }
    // peeled tail (last 8 steps): finalize on j==7
    RNN_STEP(0, false) RNN_STEP(1, false) RNN_STEP(2, false) RNN_STEP(3, false)
    RNN_STEP(4, false) RNN_STEP(5, false) RNN_STEP(6, false) RNN_STEP(7, true)
#undef RNN_STEP

    // --- Phase 3: out = sigmoid(Wya * a_last + Wyb), last chunk only
    if (is_last) {
        const int o  = tid >> 3;   // 0..127
        const int k8 = tid & 7;    // 8-way K split within wave
        const float4* wp = (const float4*)(Wya + (size_t)o * 256 + k8 * 32);
        const float4* ap = (const float4*)(afin + k8 * 32);
        float s = 0.f;
#pragma unroll
        for (int i = 0; i < 8; ++i) {
            float4 wv4 = wp[i];
            float4 a4  = ap[i];
            s += wv4.x * a4.x + wv4.y * a4.y + wv4.z * a4.z + wv4.w * a4.w;
        }
        s += __shfl_xor(s, 1);
        s += __shfl_xor(s, 2);
        s += __shfl_xor(s, 4);
        if (k8 == 0)
            out[b * 128 + o] = __builtin_amdgcn_rcpf(1.f + __expf(-(s + Wyb[o])));
    }
}

// ---------------------------------------------------------------------------
extern "C" void kernel_launch(void* const* d_in, const int* in_sizes, int n_in,
                              void* d_out, int out_size, void* d_ws, size_t ws_size,
                              hipStream_t stream)
{
    (void)in_sizes; (void)n_in; (void)out_size;
    const float* x    = (const float*)d_in[0];
    const float* Waxw = (const float*)d_in[1];
    const float* Waxb = (const float*)d_in[2];
    const float* Waaw = (const float*)d_in[3];
    const float* Waab = (const float*)d_in[4];
    const float* Wyaw = (const float*)d_in[5];
    const float* Wyab = (const float*)d_in[6];
    float* out = (float*)d_out;

    // Adaptive chunking over timesteps so the f16 xp chunk fits in d_ws.
    int T_C = 4096, logT = 12;
    while (T_C > 32 && (size_t)64 * T_C * 256 * 2 + 32768 > ws_size) { T_C >>= 1; --logT; }

    _Float16* xp = (_Float16*)d_ws;
    unsigned short* a_state =
        (unsigned short*)((char*)d_ws + (size_t)64 * T_C * 256 * 2);

    const int nc = 4096 / T_C;
    for (int ci = 0; ci < nc; ++ci) {
        k_xp<<<dim3(T_C), dim3(512), 0, stream>>>(x, Waxw, Waxb, xp, ci, T_C, logT);
        k_rnn<<<dim3(64), dim3(1024), 0, stream>>>(xp, Waaw, Waab, Wyaw, Wyab,
                                                   out, a_state, ci, T_C, ci == nc - 1);
    }
}